// Round 11
// baseline (2813.463 us; speedup 1.0000x reference)
//
#include <hip/hip_runtime.h>
#include <stdint.h>

// LSTM B=32,T=512,D=1024,H=1024 — R11: R10's split-phase structure with the
// PROVEN device-scope (sc0 sc1) exchange medium; XCD vote/fast-path removed
// (bisect: R10's fail was structure XOR medium).
// 8 groups x 4 batches x 32 blocks (G=blockIdx>>5, r=blockIdx&31).
// Phase 1: xg = x@Wx + bx + bh (f16), aliased into the hts2/cts output slabs
// (block-owned bytes only; consumed at step t before row t is overwritten).
// Scan: Wh k<512 in 128KB LDS frags + k>=512 in 64 VGPRs/thread; h exchange =
// stego-tagged dwords (bit0 of each f16 = 2-bit step counter) via sc0sc1;
// wave0 probes 8KB+copies to LDS; ONE s_barrier per step; shuffle-based gates.

typedef _Float16 f16;
typedef __attribute__((ext_vector_type(8))) _Float16 f16x8;
typedef __attribute__((ext_vector_type(4))) float f32x4;
typedef __attribute__((ext_vector_type(4))) unsigned int u32x4;

#define HTS2_F 16777216u
#define CTS_F 33554432u
#define CLS_F 50331648u

__device__ __forceinline__ float sigm(float v){ return 1.f/(1.f+__expf(-v)); }
__device__ __forceinline__ float tanh_(float v){ return 2.f/(1.f+__expf(-2.f*v)) - 1.f; }
__device__ __forceinline__ float f16b2f(uint32_t u){ union{uint16_t s; f16 f;} c; c.s=(uint16_t)u; return (float)c.f; }

__device__ __forceinline__ u32x4 ld16_dev(const void* p){
  u32x4 r; asm volatile("global_load_dwordx4 %0, %1, off sc0 sc1" : "=v"(r) : "v"(p)); return r; }
__device__ __forceinline__ void st4_dev(void* p, uint32_t v){
  asm volatile("global_store_dword %0, %1, off sc0 sc1" :: "v"(p), "v"(v) : "memory"); }

__global__ __launch_bounds__(512, 2) void lstm_kernel(
    const float* __restrict__ xin, const float* __restrict__ amask,
    const int* __restrict__ nzidx, const float* __restrict__ Wx,
    const float* __restrict__ Wh, const float* __restrict__ bx,
    const float* __restrict__ bh, float* __restrict__ out,
    uint32_t* __restrict__ ws)
{
  __shared__ __align__(16) unsigned char BigLDS[131072];  // phase1 frags/A | scan Wh k<512
  __shared__ __align__(16) f16 h_lds[2][4][1032];         // parity x batch x padded cols

  const int tid = threadIdx.x, lane = tid & 63, wid = tid >> 6;
  const int G = blockIdx.x >> 5;     // group 0..7 (batches G*4..G*4+3)
  const int r = blockIdx.x & 31;     // rank: h-cols [r*32, r*32+32)
  uint8_t* exch = (uint8_t*)ws + (size_t)G * 16384;  // 2 parity x 8KB

  const size_t bg0 = (size_t)G * 4;
  const int bb = lane & 15, kslot = lane >> 4;
  const int c16 = lane & 15;
  const int jj = lane & 3;

  // gather Wsrc k in [kbase,kbase+512) -> frag layout [f=q*16+kf][lane][8] f16
  auto gather = [&](const float* Wsrc, int kbase) {
    f16* L = (f16*)BigLDS;
#pragma unroll 1
    for (int i = 0; i < 32; ++i) {
      int idx = i * 512 + tid;
      int kp = idx >> 5, g = (idx >> 3) & 3, q = idx & 7;
      f32x4 v = *(const f32x4*)(Wsrc + (size_t)(kbase + kp) * 4096 + g * 1024 + r * 32 + q * 4);
      int f = q * 16 + (kp >> 5);
      int base = f * 512 + (g * 4 + 16 * ((kp >> 3) & 3)) * 8 + (kp & 7);
#pragma unroll
      for (int j2 = 0; j2 < 4; ++j2) L[base + j2 * 8] = (f16)v[j2];
    }
  };

  const int gcolb = (c16 >> 2) * 1024 + r * 32 + wid * 4 + (c16 & 3);
  const float biasv = bx[gcolb] + bh[gcolb];
  const size_t chunkF = (wid >= 4) ? (size_t)CTS_F : (size_t)HTS2_F;
  const size_t xgoff = (size_t)r * 128 + (size_t)(wid & 3) * 32 + (size_t)c16 * 2;

  // ---------------- phase 1: xg = x@Wx (+bias on pass 2), f16, aliased ----------------
#pragma unroll 1
  for (int kh = 0; kh < 2; ++kh) {
    __syncthreads();
    gather(Wx, kh * 512);
    __syncthreads();
    f16x8 BX[16];
#pragma unroll
    for (int kf = 0; kf < 16; ++kf)
      BX[kf] = *(const f16x8*)(BigLDS + (wid * 16 + kf) * 1024 + lane * 16);
    __syncthreads();
#pragma unroll 1
    for (int win = 0; win < 64; ++win) {
      { // coop stage A: 32 (b,t)-rows x 512 k (f16), rows padded to 520
        const int row = tid >> 4, seg = tid & 15;
        const int grow = win * 32 + row;
        const float* src = xin + ((bg0 + (size_t)(grow & 3)) * 512 + (size_t)(grow >> 2)) * 1024
                         + kh * 512 + seg * 32;
        f16* dst = (f16*)BigLDS + row * 520 + seg * 32;
#pragma unroll
        for (int u2 = 0; u2 < 4; ++u2) {
          f32x4 v0 = *(const f32x4*)(src + u2 * 8);
          f32x4 v1 = *(const f32x4*)(src + u2 * 8 + 4);
          f16x8 h8;
#pragma unroll
          for (int z = 0; z < 4; ++z) { h8[z] = (f16)v0[z]; h8[z + 4] = (f16)v1[z]; }
          *(f16x8*)(dst + u2 * 8) = h8;
        }
      }
      __syncthreads();
#pragma unroll 1
      for (int s = 0; s < 2; ++s) {
        f32x4 acc = {0.f, 0.f, 0.f, 0.f};
#pragma unroll
        for (int kf = 0; kf < 16; ++kf) {
          f16x8 a = *(const f16x8*)((const f16*)BigLDS + (s * 16 + bb) * 520 + kf * 32 + kslot * 8);
          acc = __builtin_amdgcn_mfma_f32_16x16x32_f16(a, BX[kf], acc, 0, 0, 0);
        }
        const int tt = (win * 2 + s) * 4 + (lane >> 4);
#pragma unroll
        for (int b2 = 0; b2 < 4; ++b2) {
          f16* p = (f16*)((uint8_t*)out
                 + 4 * (chunkF + (bg0 + b2) * 524288 + (size_t)tt * 1024) + xgoff);
          if (kh == 0) *p = (f16)acc[b2];
          else         *p = (f16)(acc[b2] + (float)*p + biasv);
        }
      }
      __syncthreads();
    }
  }

  // ---------------- Wh: VGPR half (k 512..1023), then LDS half (k 0..511) ----------------
  __syncthreads();
  gather(Wh, 512);
  __syncthreads();
  f16x8 BH[16];
#pragma unroll
  for (int kf = 0; kf < 16; ++kf)
    BH[kf] = *(const f16x8*)(BigLDS + (wid * 16 + kf) * 1024 + lane * 16);
  __syncthreads();
  gather(Wh, 0);
  __syncthreads();

  // ---------------- scan prologue ----------------
  const int mycol = r * 32 + wid * 4 + jj;
  const int mi0 = nzidx[bg0 + 0], mi1 = nzidx[bg0 + 1], mi2 = nzidx[bg0 + 2], mi3 = nzidx[bg0 + 3];
  float m0 = amask[(bg0 + 0) * 512], m1 = amask[(bg0 + 1) * 512],
        m2 = amask[(bg0 + 2) * 512], m3 = amask[(bg0 + 3) * 512];
  float c0 = 0.f, c1 = 0.f, c2 = 0.f, c3 = 0.f;
  float dh0=0.f,dh1=0.f,dh2=0.f,dh3=0.f, dc0=0.f,dc1=0.f,dc2=0.f,dc3=0.f;

  uint32_t xE0,xE1,xE2,xE3, xO0,xO1,xO2,xO3;
  {
    const uint8_t* ob = (const uint8_t*)out;
    xE0 = *(const uint16_t*)(ob + 4*(chunkF + (bg0+0)*524288) + xgoff);
    xE1 = *(const uint16_t*)(ob + 4*(chunkF + (bg0+1)*524288) + xgoff);
    xE2 = *(const uint16_t*)(ob + 4*(chunkF + (bg0+2)*524288) + xgoff);
    xE3 = *(const uint16_t*)(ob + 4*(chunkF + (bg0+3)*524288) + xgoff);
    xO0 = *(const uint16_t*)(ob + 4*(chunkF + (bg0+0)*524288 + 1024) + xgoff);
    xO1 = *(const uint16_t*)(ob + 4*(chunkF + (bg0+1)*524288 + 1024) + xgoff);
    xO2 = *(const uint16_t*)(ob + 4*(chunkF + (bg0+2)*524288 + 1024) + xgoff);
    xO3 = *(const uint16_t*)(ob + 4*(chunkF + (bg0+3)*524288 + 1024) + xgoff);
  }
  asm volatile("s_waitcnt vmcnt(0)" ::: "memory");

  auto publish = [&](float h0v, float h1v, float h2v, float h3v, int tp) {
    const uint32_t tb = ((uint32_t)(tp >> 1) + 1u) & 3u;
    const uint32_t bitv = (jj & 1) ? ((tb >> 1) & 1u) : (tb & 1u);
    union { f16 f; uint16_t u; } cv;
    cv.f = (f16)h0v; uint32_t u0 = ((uint32_t)cv.u & 0xFFFEu) | bitv;
    cv.f = (f16)h1v; uint32_t u1 = ((uint32_t)cv.u & 0xFFFEu) | bitv;
    cv.f = (f16)h2v; uint32_t u2 = ((uint32_t)cv.u & 0xFFFEu) | bitv;
    cv.f = (f16)h3v; uint32_t u3 = ((uint32_t)cv.u & 0xFFFEu) | bitv;
    uint32_t n0 = (uint32_t)__shfl((int)u0, lane + 1);
    uint32_t n1 = (uint32_t)__shfl((int)u1, lane + 1);
    uint32_t n2 = (uint32_t)__shfl((int)u2, lane + 1);
    uint32_t n3 = (uint32_t)__shfl((int)u3, lane + 1);
    if (lane < 4 && (lane & 1) == 0) {
      uint8_t* eb = exch + (size_t)(tp & 1) * 8192;
      const int dbase = r * 16 + wid * 2 + (jj >> 1);
      st4_dev(eb + (size_t)(0 * 512 + dbase) * 4, u0 | (n0 << 16));
      st4_dev(eb + (size_t)(1 * 512 + dbase) * 4, u1 | (n1 << 16));
      st4_dev(eb + (size_t)(2 * 512 + dbase) * 4, u2 | (n2 << 16));
      st4_dev(eb + (size_t)(3 * 512 + dbase) * 4, u3 | (n3 << 16));
    }
  };
  publish(0.f, 0.f, 0.f, 0.f, 0);   // h(0)=0, tagged for step 0

  bool gave_up = false;
  // ---------------- scan ----------------
#pragma unroll 1
  for (int t = 0; t < 512; ++t) {
    const int p = t & 1;
    if (wid == 0) {
      const uint8_t* eb = exch + (size_t)p * 8192;
      const uint32_t tb = ((uint32_t)(t >> 1) + 1u) & 3u;
      const uint32_t pat = (tb & 1u) | (((tb >> 1) & 1u) << 16);
      u32x4 hq[8];
      if (!gave_up) {
        bool got = false; int sp = 0;
        for (;;) {
#pragma unroll
          for (int m = 0; m < 8; ++m) hq[m] = ld16_dev(eb + (size_t)((m * 64 + lane) << 4));
          asm volatile("s_waitcnt vmcnt(0)" ::: "memory");
          __builtin_amdgcn_sched_barrier(0);
          bool okv = true;
#pragma unroll
          for (int m = 0; m < 8; ++m)
#pragma unroll
            for (int z = 0; z < 4; ++z) okv &= ((hq[m][z] & 0x00010001u) == pat);
          if (__all((int)okv)) { got = true; break; }
          if (++sp > (1 << 14)) break;
        }
        if (!got) gave_up = true;
      } else {
#pragma unroll
        for (int m = 0; m < 8; ++m) hq[m] = ld16_dev(eb + (size_t)((m * 64 + lane) << 4));
        asm volatile("s_waitcnt vmcnt(0)" ::: "memory");
        __builtin_amdgcn_sched_barrier(0);
      }
      // deferred outputs of t-1 (post-drain slack)
      if (t > 0 && lane < 4) {
        size_t o0 = ((bg0 + 0) * 512 + (size_t)(t - 1)) * 1024 + mycol;
        out[o0] = dh0; out[o0 + HTS2_F] = dh0; out[o0 + CTS_F] = dc0;  o0 += 524288;
        out[o0] = dh1; out[o0 + HTS2_F] = dh1; out[o0 + CTS_F] = dc1;  o0 += 524288;
        out[o0] = dh2; out[o0 + HTS2_F] = dh2; out[o0 + CTS_F] = dc2;  o0 += 524288;
        out[o0] = dh3; out[o0 + HTS2_F] = dh3; out[o0 + CTS_F] = dc3;
      }
      uint8_t* hl = (uint8_t*)h_lds + (size_t)p * 8256;
#pragma unroll
      for (int m = 0; m < 8; ++m) {
        int i = m * 64 + lane;
        *(u32x4*)(hl + (i >> 7) * 2064 + (i & 127) * 16) = hq[m];
      }
      asm volatile("s_waitcnt lgkmcnt(0)" ::: "memory");
      __builtin_amdgcn_sched_barrier(0);
    }
    __builtin_amdgcn_s_barrier();
    __builtin_amdgcn_sched_barrier(0);
    // ---- MFMAs: h @ Wh (LDS half k<512, VGPR half k>=512) ----
    const uint8_t* hb = (const uint8_t*)h_lds + (size_t)p * 8256 + (size_t)(bb & 3) * 2064;
    f32x4 acc = {0.f,0.f,0.f,0.f};
#pragma unroll
    for (int kf = 0; kf < 16; ++kf) {
      f16x8 a = *(const f16x8*)(hb + kf * 64 + kslot * 16);
      f16x8 b = *(const f16x8*)(BigLDS + (wid * 16 + kf) * 1024 + lane * 16);
      acc = __builtin_amdgcn_mfma_f32_16x16x32_f16(a, b, acc, 0, 0, 0);
    }
#pragma unroll
    for (int kf = 0; kf < 16; ++kf) {
      f16x8 a = *(const f16x8*)(hb + 1024 + kf * 64 + kslot * 16);
      acc = __builtin_amdgcn_mfma_f32_16x16x32_f16(a, BH[kf], acc, 0, 0, 0);
    }
    // ---- gates (shuffle redistribution from lanes 0..15) ----
    float s0, s1, s2, s3;
    if (p == 0) { s0 = acc[0] + f16b2f(xE0); s1 = acc[1] + f16b2f(xE1);
                  s2 = acc[2] + f16b2f(xE2); s3 = acc[3] + f16b2f(xE3); }
    else        { s0 = acc[0] + f16b2f(xO0); s1 = acc[1] + f16b2f(xO1);
                  s2 = acc[2] + f16b2f(xO2); s3 = acc[3] + f16b2f(xO3); }
    const bool isg = ((c16 >> 2) == 2);
    const float a0 = isg ? tanh_(s0) : sigm(s0);
    const float a1 = isg ? tanh_(s1) : sigm(s1);
    const float a2 = isg ? tanh_(s2) : sigm(s2);
    const float a3 = isg ? tanh_(s3) : sigm(s3);
    const float iv0 = __shfl(a0, jj), fv0 = __shfl(a0, 4+jj), gv0 = __shfl(a0, 8+jj), ov0 = __shfl(a0, 12+jj);
    const float iv1 = __shfl(a1, jj), fv1 = __shfl(a1, 4+jj), gv1 = __shfl(a1, 8+jj), ov1 = __shfl(a1, 12+jj);
    const float iv2 = __shfl(a2, jj), fv2 = __shfl(a2, 4+jj), gv2 = __shfl(a2, 8+jj), ov2 = __shfl(a2, 12+jj);
    const float iv3 = __shfl(a3, jj), fv3 = __shfl(a3, 4+jj), gv3 = __shfl(a3, 8+jj), ov3 = __shfl(a3, 12+jj);
    c0 = fv0 * c0 + iv0 * gv0; const float hv0 = ov0 * tanh_(c0);
    c1 = fv1 * c1 + iv1 * gv1; const float hv1 = ov1 * tanh_(c1);
    c2 = fv2 * c2 + iv2 * gv2; const float hv2 = ov2 * tanh_(c2);
    c3 = fv3 * c3 + iv3 * gv3; const float hv3 = ov3 * tanh_(c3);
    // drain older vmem, publish h(t+1), then prefetch xg(t+2)
    asm volatile("s_waitcnt vmcnt(0)" ::: "memory");
    if (t < 511) publish(hv0, hv1, hv2, hv3, t + 1);
    if (t + 2 < 512) {
      const uint8_t* ob = (const uint8_t*)out;
      const size_t t2 = (size_t)(t + 2) * 1024;
      if (p == 0) {
        xE0 = *(const uint16_t*)(ob + 4*(chunkF + (bg0+0)*524288 + t2) + xgoff);
        xE1 = *(const uint16_t*)(ob + 4*(chunkF + (bg0+1)*524288 + t2) + xgoff);
        xE2 = *(const uint16_t*)(ob + 4*(chunkF + (bg0+2)*524288 + t2) + xgoff);
        xE3 = *(const uint16_t*)(ob + 4*(chunkF + (bg0+3)*524288 + t2) + xgoff);
      } else {
        xO0 = *(const uint16_t*)(ob + 4*(chunkF + (bg0+0)*524288 + t2) + xgoff);
        xO1 = *(const uint16_t*)(ob + 4*(chunkF + (bg0+1)*524288 + t2) + xgoff);
        xO2 = *(const uint16_t*)(ob + 4*(chunkF + (bg0+2)*524288 + t2) + xgoff);
        xO3 = *(const uint16_t*)(ob + 4*(chunkF + (bg0+3)*524288 + t2) + xgoff);
      }
    }
    // outputs
    const float hm0 = hv0 * m0, cm0 = c0 * m0;
    const float hm1 = hv1 * m1, cm1 = c1 * m1;
    const float hm2 = hv2 * m2, cm2 = c2 * m2;
    const float hm3 = hv3 * m3, cm3 = c3 * m3;
    if (wid == 0) { dh0 = hm0; dc0 = cm0; dh1 = hm1; dc1 = cm1;
                    dh2 = hm2; dc2 = cm2; dh3 = hm3; dc3 = cm3; }
    else if (lane < 4) {
      size_t o0 = ((bg0 + 0) * 512 + (size_t)t) * 1024 + mycol;
      out[o0] = hm0; out[o0 + HTS2_F] = hm0; out[o0 + CTS_F] = cm0;  o0 += 524288;
      out[o0] = hm1; out[o0 + HTS2_F] = hm1; out[o0 + CTS_F] = cm1;  o0 += 524288;
      out[o0] = hm2; out[o0 + HTS2_F] = hm2; out[o0 + CTS_F] = cm2;  o0 += 524288;
      out[o0] = hm3; out[o0 + HTS2_F] = hm3; out[o0 + CTS_F] = cm3;
    }
    if (lane < 4) {
      if (t == mi0) out[CLS_F + (bg0 + 0) * 1024 + mycol] = hv0;
      if (t == mi1) out[CLS_F + (bg0 + 1) * 1024 + mycol] = hv1;
      if (t == mi2) out[CLS_F + (bg0 + 2) * 1024 + mycol] = hv2;
      if (t == mi3) out[CLS_F + (bg0 + 3) * 1024 + mycol] = hv3;
    }
    if (t + 1 < 512) {
      m0 = amask[(bg0 + 0) * 512 + t + 1]; m1 = amask[(bg0 + 1) * 512 + t + 1];
      m2 = amask[(bg0 + 2) * 512 + t + 1]; m3 = amask[(bg0 + 3) * 512 + t + 1];
    }
  }
  // final deferred flush (t = 511)
  if (wid == 0 && lane < 4) {
    size_t o0 = ((bg0 + 0) * 512 + 511) * 1024 + mycol;
    out[o0] = dh0; out[o0 + HTS2_F] = dh0; out[o0 + CTS_F] = dc0;  o0 += 524288;
    out[o0] = dh1; out[o0 + HTS2_F] = dh1; out[o0 + CTS_F] = dc1;  o0 += 524288;
    out[o0] = dh2; out[o0 + HTS2_F] = dh2; out[o0 + CTS_F] = dc2;  o0 += 524288;
    out[o0] = dh3; out[o0 + HTS2_F] = dh3; out[o0 + CTS_F] = dc3;
  }
}

extern "C" void kernel_launch(void* const* d_in, const int* in_sizes, int n_in,
                              void* d_out, int out_size, void* d_ws, size_t ws_size,
                              hipStream_t stream) {
  (void)in_sizes; (void)n_in; (void)out_size; (void)ws_size;
  const float* xin   = (const float*)d_in[0];
  const float* amask = (const float*)d_in[1];
  const int*   nzidx = (const int*)d_in[2];
  const float* Wx    = (const float*)d_in[3];
  const float* Wh    = (const float*)d_in[4];
  const float* bx    = (const float*)d_in[5];
  const float* bh    = (const float*)d_in[6];
  float* out = (float*)d_out;
  uint32_t* ws = (uint32_t*)d_ws;

  // zero the exchange regions every launch (tags expect zero-init)
  hipMemsetAsync(d_ws, 0, 8 * 16384, stream);

  void* args[] = {(void*)&xin, (void*)&amask, (void*)&nzidx, (void*)&Wx,
                  (void*)&Wh, (void*)&bx, (void*)&bh, (void*)&out, (void*)&ws};
  hipError_t e = hipLaunchCooperativeKernel((const void*)lstm_kernel, dim3(256), dim3(512),
                                            args, 0, stream);
  if (e != hipSuccess) {
    lstm_kernel<<<dim3(256), dim3(512), 0, stream>>>(xin, amask, nzidx, Wx, Wh, bx, bh, out, ws);
  }
}